// Round 3
// baseline (473.770 us; speedup 1.0000x reference)
//
#include <hip/hip_runtime.h>
#include <math.h>

#define SEQ 4096
#define CH  256
#define NHT 8      // N * HEADS
#define DHD 64

using bf16x8 = __attribute__((ext_vector_type(8))) short;
using f32x4  = __attribute__((ext_vector_type(4))) float;
typedef unsigned short u16;
typedef unsigned int   u32;

__device__ __forceinline__ u16 f2bf(float f) {
    u32 u = __float_as_uint(f);
    u = (u + 0x7fffu + ((u >> 16) & 1u)) >> 16;
    return (u16)u;
}
__device__ __forceinline__ float bf2f(u16 h) {
    return __uint_as_float(((u32)h) << 16);
}

// ---------------------------------------------------------------------------
// Weight pack (transposed for NT GEMM).
// ---------------------------------------------------------------------------
__global__ __launch_bounds__(256) void k_pack(const float* __restrict__ WQ,
                                              const float* __restrict__ WK,
                                              const float* __restrict__ WV,
                                              const float* __restrict__ W1,
                                              const float* __restrict__ W2,
                                              u16* __restrict__ BtQKV,
                                              u16* __restrict__ W1t,
                                              u16* __restrict__ W2t)
{
    int id = blockIdx.x * 256 + threadIdx.x;
    if (id < 768 * 256) {
        int j = id >> 8, c = id & 255;
        int which = j >> 8, h = (j >> 6) & 3, d = j & 63;
        const float* W = (which == 0) ? WQ : (which == 1) ? WK : WV;
        BtQKV[id] = f2bf(W[(h * 256 + c) * 64 + d]);
    } else if (id < 768 * 256 + 65536) {
        int jj = id - 768 * 256;
        int j = jj >> 8, c = jj & 255;
        W1t[jj] = f2bf(W1[c * 256 + j]);
    } else if (id < 768 * 256 + 2 * 65536) {
        int jj = id - 768 * 256 - 65536;
        int j = jj >> 8, c = jj & 255;
        W2t[jj] = f2bf(W2[c * 256 + j]);
    }
}

// ---------------------------------------------------------------------------
// LN1: x [N][C][S] -> norm bf16 [N][S][C]. 16 s-rows per block, 512 blocks.
// ---------------------------------------------------------------------------
__global__ __launch_bounds__(256) void k_ln1(const float* __restrict__ x,
                                             const float* __restrict__ w,
                                             const float* __restrict__ b,
                                             u16* __restrict__ norm)
{
    __shared__ float tile[16][257];
    __shared__ float mu[16], rs[16];
    int n = blockIdx.y, s0 = blockIdx.x * 16;
    int t = threadIdx.x;
    int sl = t & 15, cg = t >> 4;          // 16 c per pass
    for (int cc = 0; cc < 256; cc += 16) {
        int c = cc + cg;
        tile[sl][c] = x[(n * 256 + c) * SEQ + s0 + sl];
    }
    __syncthreads();
    int wv = t >> 6, l = t & 63;
    for (int rr = 0; rr < 4; rr++) {
        int s = wv * 4 + rr;
        float a0 = tile[s][l], a1 = tile[s][l + 64], a2 = tile[s][l + 128], a3 = tile[s][l + 192];
        float sm = a0 + a1 + a2 + a3;
        float sq = a0 * a0 + a1 * a1 + a2 * a2 + a3 * a3;
        for (int off = 32; off; off >>= 1) { sm += __shfl_xor(sm, off); sq += __shfl_xor(sq, off); }
        if (l == 0) {
            float m = sm * (1.f / 256.f);
            mu[s] = m;
            rs[s] = rsqrtf(sq * (1.f / 256.f) - m * m + 1e-5f);
        }
    }
    __syncthreads();
    float ww = w[t], bb = b[t];
    for (int s = 0; s < 16; s++) {
        float v = (tile[s][t] - mu[s]) * rs[s] * ww + bb;
        norm[(n * SEQ + s0 + s) * 256 + t] = f2bf(v);
    }
}

// ---------------------------------------------------------------------------
// QKV projection, single-barrier: A 64x256 staged in LDS, B frags straight
// from global (weights, L2-resident). Grid (128 M-tiles, 6 N-tiles).
// ---------------------------------------------------------------------------
__global__ __launch_bounds__(256) void k_qkv(const u16* __restrict__ norm,
                                             const u16* __restrict__ Bt,
                                             u16* __restrict__ Qo,
                                             u16* __restrict__ Ko,
                                             u16* __restrict__ Vo)
{
    __shared__ __align__(16) u16 lA[64][264];
    int m0 = blockIdx.x * 64, j0 = blockIdx.y * 128;
    int t = threadIdx.x, w = t >> 6, lane = t & 63, quad = lane >> 4, l16 = lane & 15;
    #pragma unroll
    for (int p = 0; p < 8; p++) {
        int idx = p * 256 + t;
        int row = idx >> 5, ch = (idx & 31) * 8;
        *(uint4*)&lA[row][ch] = *(const uint4*)&norm[(long)(m0 + row) * 256 + ch];
    }
    __syncthreads();
    f32x4 z = {0.f, 0.f, 0.f, 0.f};
    f32x4 acc[8];
    #pragma unroll
    for (int j = 0; j < 8; j++) acc[j] = z;
    const u16* Bp = Bt + (long)j0 * 256;
    #pragma unroll
    for (int kc = 0; kc < 8; kc++) {
        bf16x8 a = *(const bf16x8*)&lA[w * 16 + l16][kc * 32 + quad * 8];
        #pragma unroll
        for (int j = 0; j < 8; j++) {
            bf16x8 b = *(const bf16x8*)&Bp[(long)(j * 16 + l16) * 256 + kc * 32 + quad * 8];
            acc[j] = __builtin_amdgcn_mfma_f32_16x16x32_bf16(a, b, acc[j], 0, 0, 0);
        }
    }
    #pragma unroll
    for (int j = 0; j < 8; j++) {
        int col = j0 + j * 16 + l16;
        int which = col >> 8, h = (col >> 6) & 3, d = col & 63;
        u16* dst = (which == 0) ? Qo : (which == 1) ? Ko : Vo;
        #pragma unroll
        for (int r = 0; r < 4; r++) {
            int m = m0 + w * 16 + quad * 4 + r;
            int n = m >> 12, s = m & 4095;
            dst[((n * 4 + h) * SEQ + s) * 64 + d] = f2bf(acc[j][r]);
        }
    }
}

// ---------------------------------------------------------------------------
// Pass 1: partial column sums D8[qc][nh][k] = sum_q exp(QK^T/64). S^T form,
// K frags in registers, Q frags straight from global. NO LDS, NO barriers.
// Grid (32 k-tiles, 8 nh, 8 q-chunks of 512).
// ---------------------------------------------------------------------------
__global__ __launch_bounds__(256) void k_pass1(const u16* __restrict__ Q,
                                               const u16* __restrict__ Km,
                                               float* __restrict__ D8)
{
    int nh = blockIdx.y, k0 = blockIdx.x * 128, qc = blockIdx.z;
    const u16* Qh = Q + (long)nh * SEQ * 64;
    const u16* Kh = Km + (long)nh * SEQ * 64;
    int t = threadIdx.x, w = t >> 6, lane = t & 63, quad = lane >> 4, l16 = lane & 15;
    bf16x8 Kf[2][2];
    #pragma unroll
    for (int i = 0; i < 2; i++)
        #pragma unroll
        for (int ch = 0; ch < 2; ch++)
            Kf[i][ch] = *(const bf16x8*)&Kh[(k0 + w * 32 + i * 16 + l16) * 64 + ch * 32 + quad * 8];
    f32x4 z = {0.f, 0.f, 0.f, 0.f};
    float Dacc[2][4] = {{0.f, 0.f, 0.f, 0.f}, {0.f, 0.f, 0.f, 0.f}};
    const float C = 0.015625f * 1.44269504088896f;   // log2(e)/64
    for (int q = qc * 512; q < qc * 512 + 512; q += 16) {
        bf16x8 b0 = *(const bf16x8*)&Qh[(q + l16) * 64 + quad * 8];
        bf16x8 b1 = *(const bf16x8*)&Qh[(q + l16) * 64 + 32 + quad * 8];
        #pragma unroll
        for (int i = 0; i < 2; i++) {
            f32x4 acc = z;
            acc = __builtin_amdgcn_mfma_f32_16x16x32_bf16(Kf[i][0], b0, acc, 0, 0, 0);
            acc = __builtin_amdgcn_mfma_f32_16x16x32_bf16(Kf[i][1], b1, acc, 0, 0, 0);
            #pragma unroll
            for (int r = 0; r < 4; r++) Dacc[i][r] += exp2f(acc[r] * C);
        }
    }
    #pragma unroll
    for (int i = 0; i < 2; i++)
        #pragma unroll
        for (int r = 0; r < 4; r++) {
            float v = Dacc[i][r];
            v += __shfl_xor(v, 1); v += __shfl_xor(v, 2);
            v += __shfl_xor(v, 4); v += __shfl_xor(v, 8);
            if (l16 == 0)
                D8[((long)(qc * NHT + nh)) * SEQ + k0 + w * 32 + i * 16 + quad * 4 + r] = v;
        }
}

// ---------------------------------------------------------------------------
// Scale+transpose V: Vt[nh][d][k] = V[nh][k][d] / D[nh][k], D = sum of 8
// pass-1 partials.
// ---------------------------------------------------------------------------
__global__ __launch_bounds__(256) void k_scaleV(const u16* __restrict__ V,
                                                const float* __restrict__ D8,
                                                u16* __restrict__ Vt)
{
    __shared__ float tile[64][65];
    int nh = blockIdx.y, k0 = blockIdx.x * 64;
    int t = threadIdx.x;
    int d = t & 63, kk = t >> 6;
    const u16* Vh = V + (long)nh * SEQ * 64;
    for (int p = 0; p < 16; p++) {
        int k = p * 4 + kk;
        float Dv = 0.f;
        #pragma unroll
        for (int qc = 0; qc < 8; qc++)
            Dv += D8[((long)(qc * NHT + nh)) * SEQ + k0 + k];
        tile[k][d] = bf2f(Vh[(k0 + k) * 64 + d]) * (1.f / Dv);
    }
    __syncthreads();
    int k2 = t & 63, d4 = t >> 6;
    u16* Vth = Vt + (long)nh * 64 * SEQ;
    for (int p = 0; p < 16; p++) {
        int dd = p * 4 + d4;
        Vth[dd * SEQ + k0 + k2] = f2bf(tile[k2][dd]);
    }
}

// ---------------------------------------------------------------------------
// Pass 2: attn partial = exp(QK^T/64) @ (V/D) over a 1024-k chunk, atomically
// accumulated into acat (pre-zeroed). S^T trick for packed lP writes. K and
// V^T frags straight from global (L2). LDS = lP only (17.4 KB) -> high occ.
// Grid (64 q-tiles, 8 nh, 4 k-chunks).
// ---------------------------------------------------------------------------
__global__ __launch_bounds__(256) void k_pass2(const u16* __restrict__ Q,
                                               const u16* __restrict__ Km,
                                               const u16* __restrict__ Vt,
                                               float* __restrict__ acat)
{
    __shared__ __align__(16) u16 lP[64][136];
    int nh = blockIdx.y, q0 = blockIdx.x * 64, kbase = blockIdx.z * 1024;
    int n = nh >> 2, h = nh & 3;
    const u16* Qh = Q + (long)nh * SEQ * 64;
    const u16* Kh = Km + (long)nh * SEQ * 64;
    const u16* Vh = Vt + (long)nh * 64 * SEQ;
    int t = threadIdx.x, w = t >> 6, lane = t & 63, quad = lane >> 4, l16 = lane & 15;
    bf16x8 Qf[4][2];
    #pragma unroll
    for (int j = 0; j < 4; j++)
        #pragma unroll
        for (int ch = 0; ch < 2; ch++)
            Qf[j][ch] = *(const bf16x8*)&Qh[(q0 + j * 16 + l16) * 64 + ch * 32 + quad * 8];
    f32x4 z = {0.f, 0.f, 0.f, 0.f};
    f32x4 accO[4];
    #pragma unroll
    for (int jd = 0; jd < 4; jd++) accO[jd] = z;
    const float C = 0.015625f * 1.44269504088896f;

    for (int k0 = kbase; k0 < kbase + 1024; k0 += 128) {
        // ST: wave w computes k rows [w*32, +32) x 64 q, packed writes to lP
        #pragma unroll
        for (int i = 0; i < 2; i++) {
            bf16x8 a0 = *(const bf16x8*)&Kh[(k0 + w * 32 + i * 16 + l16) * 64 + quad * 8];
            bf16x8 a1 = *(const bf16x8*)&Kh[(k0 + w * 32 + i * 16 + l16) * 64 + 32 + quad * 8];
            #pragma unroll
            for (int j = 0; j < 4; j++) {
                f32x4 acc = z;
                acc = __builtin_amdgcn_mfma_f32_16x16x32_bf16(a0, Qf[j][0], acc, 0, 0, 0);
                acc = __builtin_amdgcn_mfma_f32_16x16x32_bf16(a1, Qf[j][1], acc, 0, 0, 0);
                u16 p0 = f2bf(exp2f(acc[0] * C));
                u16 p1 = f2bf(exp2f(acc[1] * C));
                u16 p2 = f2bf(exp2f(acc[2] * C));
                u16 p3 = f2bf(exp2f(acc[3] * C));
                uint2 pk;
                pk.x = (u32)p0 | ((u32)p1 << 16);
                pk.y = (u32)p2 | ((u32)p3 << 16);
                *(uint2*)&lP[j * 16 + l16][w * 32 + i * 16 + quad * 4] = pk;
            }
        }
        __syncthreads();
        // PV: wave w owns q rows [w*16, +16)
        #pragma unroll
        for (int kc = 0; kc < 4; kc++) {
            bf16x8 pa = *(const bf16x8*)&lP[w * 16 + l16][kc * 32 + quad * 8];
            #pragma unroll
            for (int jd = 0; jd < 4; jd++) {
                bf16x8 vb = *(const bf16x8*)&Vh[(jd * 16 + l16) * SEQ + k0 + kc * 32 + quad * 8];
                accO[jd] = __builtin_amdgcn_mfma_f32_16x16x32_bf16(pa, vb, accO[jd], 0, 0, 0);
            }
        }
        __syncthreads();
    }
    #pragma unroll
    for (int jd = 0; jd < 4; jd++)
        #pragma unroll
        for (int r = 0; r < 4; r++) {
            int s = q0 + w * 16 + quad * 4 + r;
            int c = h * 64 + jd * 16 + l16;
            unsafeAtomicAdd(&acat[((long)n * SEQ + s) * 256 + c], accO[jd][r]);
        }
}

// ---------------------------------------------------------------------------
// LN2: h2 = LN(attn_cat + x^T) bf16. 16 s-rows per block, 512 blocks.
// ---------------------------------------------------------------------------
__global__ __launch_bounds__(256) void k_ln2(const float* __restrict__ x,
                                             const float* __restrict__ acat,
                                             const float* __restrict__ w,
                                             const float* __restrict__ b,
                                             u16* __restrict__ h2)
{
    __shared__ float tile[16][257];
    __shared__ float mu[16], rs[16];
    int n = blockIdx.y, s0 = blockIdx.x * 16;
    int t = threadIdx.x;
    int sl = t & 15, cg = t >> 4;
    for (int cc = 0; cc < 256; cc += 16) {
        int c = cc + cg;
        tile[sl][c] = x[(n * 256 + c) * SEQ + s0 + sl];
    }
    __syncthreads();
    for (int s = 0; s < 16; s++)
        tile[s][t] += acat[((long)n * SEQ + s0 + s) * 256 + t];
    __syncthreads();
    int wv = t >> 6, l = t & 63;
    for (int rr = 0; rr < 4; rr++) {
        int s = wv * 4 + rr;
        float a0 = tile[s][l], a1 = tile[s][l + 64], a2 = tile[s][l + 128], a3 = tile[s][l + 192];
        float sm = a0 + a1 + a2 + a3;
        float sq = a0 * a0 + a1 * a1 + a2 * a2 + a3 * a3;
        for (int off = 32; off; off >>= 1) { sm += __shfl_xor(sm, off); sq += __shfl_xor(sq, off); }
        if (l == 0) {
            float m = sm * (1.f / 256.f);
            mu[s] = m;
            rs[s] = rsqrtf(sq * (1.f / 256.f) - m * m + 1e-5f);
        }
    }
    __syncthreads();
    float ww = w[t], bb = b[t];
    for (int s = 0; s < 16; s++) {
        float v = (tile[s][t] - mu[s]) * rs[s] * ww + bb;
        h2[((long)n * SEQ + s0 + s) * 256 + t] = f2bf(v);
    }
}

// ---------------------------------------------------------------------------
// MLP1: t = gelu(h2 @ W1 + b1), single-barrier structure. Grid (128, 2).
// ---------------------------------------------------------------------------
__global__ __launch_bounds__(256) void k_mlp1(const u16* __restrict__ h2,
                                              const u16* __restrict__ W1t,
                                              const float* __restrict__ b1,
                                              u16* __restrict__ tbuf)
{
    __shared__ __align__(16) u16 lA[64][264];
    int m0 = blockIdx.x * 64, j0 = blockIdx.y * 128;
    int t = threadIdx.x, w = t >> 6, lane = t & 63, quad = lane >> 4, l16 = lane & 15;
    #pragma unroll
    for (int p = 0; p < 8; p++) {
        int idx = p * 256 + t;
        int row = idx >> 5, ch = (idx & 31) * 8;
        *(uint4*)&lA[row][ch] = *(const uint4*)&h2[(long)(m0 + row) * 256 + ch];
    }
    __syncthreads();
    f32x4 z = {0.f, 0.f, 0.f, 0.f};
    f32x4 acc[8];
    #pragma unroll
    for (int j = 0; j < 8; j++) acc[j] = z;
    const u16* Bp = W1t + (long)j0 * 256;
    #pragma unroll
    for (int kc = 0; kc < 8; kc++) {
        bf16x8 a = *(const bf16x8*)&lA[w * 16 + l16][kc * 32 + quad * 8];
        #pragma unroll
        for (int j = 0; j < 8; j++) {
            bf16x8 b = *(const bf16x8*)&Bp[(long)(j * 16 + l16) * 256 + kc * 32 + quad * 8];
            acc[j] = __builtin_amdgcn_mfma_f32_16x16x32_bf16(a, b, acc[j], 0, 0, 0);
        }
    }
    #pragma unroll
    for (int j = 0; j < 8; j++) {
        int col = j0 + j * 16 + l16;
        float bj = b1[col];
        #pragma unroll
        for (int r = 0; r < 4; r++) {
            int m = m0 + w * 16 + quad * 4 + r;
            float v = acc[j][r] + bj;
            float g = 0.5f * v * (1.f + erff(v * 0.70710678118f));
            tbuf[(long)m * 256 + col] = f2bf(g);
        }
    }
}

// ---------------------------------------------------------------------------
// MLP2 + residual + fused output transpose: out[n][c][s] directly.
// Grid (128 M-tiles, 2 N-tiles).
// ---------------------------------------------------------------------------
__global__ __launch_bounds__(256) void k_mlp2(const u16* __restrict__ tbuf,
                                              const u16* __restrict__ W2t,
                                              const float* __restrict__ b2,
                                              const float* __restrict__ acat,
                                              float* __restrict__ out)
{
    __shared__ __align__(16) unsigned char smem[128 * 68 * 4];  // 34816 B
    u16 (*lA)[264] = (u16(*)[264])smem;            // 64*264*2 = 33792 B
    float (*LT)[68] = (float(*)[68])smem;          // 128*68*4

    int m0 = blockIdx.x * 64, j0 = blockIdx.y * 128;
    int t = threadIdx.x, w = t >> 6, lane = t & 63, quad = lane >> 4, l16 = lane & 15;
    #pragma unroll
    for (int p = 0; p < 8; p++) {
        int idx = p * 256 + t;
        int row = idx >> 5, ch = (idx & 31) * 8;
        *(uint4*)&lA[row][ch] = *(const uint4*)&tbuf[(long)(m0 + row) * 256 + ch];
    }
    __syncthreads();
    f32x4 z = {0.f, 0.f, 0.f, 0.f};
    f32x4 acc[8];
    #pragma unroll
    for (int j = 0; j < 8; j++) acc[j] = z;
    const u16* Bp = W2t + (long)j0 * 256;
    #pragma unroll
    for (int kc = 0; kc < 8; kc++) {
        bf16x8 a = *(const bf16x8*)&lA[w * 16 + l16][kc * 32 + quad * 8];
        #pragma unroll
        for (int j = 0; j < 8; j++) {
            bf16x8 b = *(const bf16x8*)&Bp[(long)(j * 16 + l16) * 256 + kc * 32 + quad * 8];
            acc[j] = __builtin_amdgcn_mfma_f32_16x16x32_bf16(a, b, acc[j], 0, 0, 0);
        }
    }
    // epilogue: add bias + attn residual, then LDS transpose
    float val[8][4];
    #pragma unroll
    for (int j = 0; j < 8; j++) {
        int col = j0 + j * 16 + l16;
        float bj = b2[col];
        #pragma unroll
        for (int r = 0; r < 4; r++) {
            int m = m0 + w * 16 + quad * 4 + r;
            val[j][r] = acc[j][r] + bj + acat[(long)m * 256 + col];
        }
    }
    __syncthreads();   // all lA reads done before overwrite
    #pragma unroll
    for (int j = 0; j < 8; j++) {
        float4 fv = make_float4(val[j][0], val[j][1], val[j][2], val[j][3]);
        *(float4*)&LT[j * 16 + l16][w * 16 + quad * 4] = fv;
    }
    __syncthreads();
    int n = m0 >> 12, sbase = m0 & 4095;
    #pragma unroll
    for (int p = 0; p < 8; p++) {
        int row = p * 16 + (t >> 4);
        int ch = (t & 15) * 4;
        float4 v = *(float4*)&LT[row][ch];
        *(float4*)&out[((long)n * 256 + j0 + row) * SEQ + sbase + ch] = v;
    }
}

// ---------------------------------------------------------------------------
extern "C" void kernel_launch(void* const* d_in, const int* in_sizes, int n_in,
                              void* d_out, int out_size, void* d_ws, size_t ws_size,
                              hipStream_t stream) {
    const float* x    = (const float*)d_in[0];
    const float* ln1w = (const float*)d_in[1];
    const float* ln1b = (const float*)d_in[2];
    const float* WQ   = (const float*)d_in[3];
    const float* WK   = (const float*)d_in[4];
    const float* WV   = (const float*)d_in[5];
    const float* ln2w = (const float*)d_in[6];
    const float* ln2b = (const float*)d_in[7];
    const float* W1   = (const float*)d_in[8];
    const float* b1   = (const float*)d_in[9];
    const float* W2   = (const float*)d_in[10];
    const float* b2   = (const float*)d_in[11];
    float* out = (float*)d_out;

    char* p = (char*)d_ws;
    u16* norm   = (u16*)p;   p += (size_t)8192 * 256 * 2;
    u16* BtQKV  = (u16*)p;   p += (size_t)768 * 256 * 2;
    u16* W1t    = (u16*)p;   p += (size_t)256 * 256 * 2;
    u16* W2t    = (u16*)p;   p += (size_t)256 * 256 * 2;
    u16* Qb     = (u16*)p;   p += (size_t)NHT * SEQ * 64 * 2;
    u16* Kb     = (u16*)p;   p += (size_t)NHT * SEQ * 64 * 2;
    u16* Vb     = (u16*)p;   p += (size_t)NHT * SEQ * 64 * 2;
    float* D8   = (float*)p; p += (size_t)8 * NHT * SEQ * 4;
    u16* Vt     = (u16*)p;   p += (size_t)NHT * SEQ * 64 * 2;
    float* acat = (float*)p; p += (size_t)8192 * 256 * 4;
    u16* h2     = (u16*)p;   p += (size_t)8192 * 256 * 2;
    u16* tbuf   = (u16*)p;   p += (size_t)8192 * 256 * 2;

    k_pack<<<1280, 256, 0, stream>>>(WQ, WK, WV, W1, W2, BtQKV, W1t, W2t);
    k_ln1<<<dim3(256, 2), 256, 0, stream>>>(x, ln1w, ln1b, norm);
    k_qkv<<<dim3(128, 6), 256, 0, stream>>>(norm, BtQKV, Qb, Kb, Vb);
    k_pass1<<<dim3(32, 8, 8), 256, 0, stream>>>(Qb, Kb, D8);
    k_scaleV<<<dim3(64, 8), 256, 0, stream>>>(Vb, D8, Vt);
    hipMemsetAsync(acat, 0, (size_t)8192 * 256 * 4, stream);
    k_pass2<<<dim3(64, 8, 4), 256, 0, stream>>>(Qb, Kb, Vt, acat);
    k_ln2<<<dim3(256, 2), 256, 0, stream>>>(x, acat, ln2w, ln2b, h2);
    k_mlp1<<<dim3(128, 2), 256, 0, stream>>>(h2, W1t, b1, tbuf);
    k_mlp2<<<dim3(128, 2), 256, 0, stream>>>(tbuf, W2t, b2, acat, out);
}

// Round 4
// 382.334 us; speedup vs baseline: 1.2392x; 1.2392x over previous
//
#include <hip/hip_runtime.h>
#include <math.h>

#define SEQ 4096
#define CH  256
#define NHT 8      // N * HEADS
#define DHD 64

using bf16x8 = __attribute__((ext_vector_type(8))) short;
using f32x4  = __attribute__((ext_vector_type(4))) float;
typedef unsigned short u16;
typedef unsigned int   u32;

__device__ __forceinline__ u16 f2bf(float f) {
    u32 u = __float_as_uint(f);
    u = (u + 0x7fffu + ((u >> 16) & 1u)) >> 16;
    return (u16)u;
}
__device__ __forceinline__ float bf2f(u16 h) {
    return __uint_as_float(((u32)h) << 16);
}

// ---------------------------------------------------------------------------
// Weight pack (transposed for NT GEMM).
// ---------------------------------------------------------------------------
__global__ __launch_bounds__(256) void k_pack(const float* __restrict__ WQ,
                                              const float* __restrict__ WK,
                                              const float* __restrict__ WV,
                                              const float* __restrict__ W1,
                                              const float* __restrict__ W2,
                                              u16* __restrict__ BtQKV,
                                              u16* __restrict__ W1t,
                                              u16* __restrict__ W2t)
{
    int id = blockIdx.x * 256 + threadIdx.x;
    if (id < 768 * 256) {
        int j = id >> 8, c = id & 255;
        int which = j >> 8, h = (j >> 6) & 3, d = j & 63;
        const float* W = (which == 0) ? WQ : (which == 1) ? WK : WV;
        BtQKV[id] = f2bf(W[(h * 256 + c) * 64 + d]);
    } else if (id < 768 * 256 + 65536) {
        int jj = id - 768 * 256;
        int j = jj >> 8, c = jj & 255;
        W1t[jj] = f2bf(W1[c * 256 + j]);
    } else if (id < 768 * 256 + 2 * 65536) {
        int jj = id - 768 * 256 - 65536;
        int j = jj >> 8, c = jj & 255;
        W2t[jj] = f2bf(W2[c * 256 + j]);
    }
}

// ---------------------------------------------------------------------------
// LN1 (R2-proven): x [N][C][S] -> norm bf16 [N][S][C]. 32 s-rows per block.
// ---------------------------------------------------------------------------
__global__ __launch_bounds__(256) void k_ln1(const float* __restrict__ x,
                                             const float* __restrict__ w,
                                             const float* __restrict__ b,
                                             u16* __restrict__ norm)
{
    __shared__ float tile[32][257];
    __shared__ float mu[32], rs[32];
    int n = blockIdx.y, s0 = blockIdx.x * 32;
    int t = threadIdx.x;
    int sl = t & 31, cg = t >> 5;
    for (int cc = 0; cc < 256; cc += 8) {
        int c = cc + cg;
        tile[sl][c] = x[(n * 256 + c) * SEQ + s0 + sl];
    }
    __syncthreads();
    int wv = t >> 6, l = t & 63;
    for (int rr = 0; rr < 8; rr++) {
        int s = wv * 8 + rr;
        float a0 = tile[s][l], a1 = tile[s][l + 64], a2 = tile[s][l + 128], a3 = tile[s][l + 192];
        float sm = a0 + a1 + a2 + a3;
        float sq = a0 * a0 + a1 * a1 + a2 * a2 + a3 * a3;
        for (int off = 32; off; off >>= 1) { sm += __shfl_xor(sm, off); sq += __shfl_xor(sq, off); }
        if (l == 0) {
            float m = sm * (1.f / 256.f);
            mu[s] = m;
            rs[s] = rsqrtf(sq * (1.f / 256.f) - m * m + 1e-5f);
        }
    }
    __syncthreads();
    float ww = w[t & 255], bb = b[t & 255];
    for (int s = 0; s < 32; s++) {
        float v = (tile[s][t] - mu[s]) * rs[s] * ww + bb;
        norm[(n * SEQ + s0 + s) * 256 + t] = f2bf(v);
    }
}

// ---------------------------------------------------------------------------
// QKV projection, BARRIER-FREE: each wave computes 16 m-rows x 128 j-cols
// with A and B fragments loaded directly from global (both 16-line loads,
// L2-resident B). No LDS, no __syncthreads -> latency-tolerant.
// Grid (128 m-tiles of 64, 6 j-tiles of 128).
// ---------------------------------------------------------------------------
__global__ __launch_bounds__(256) void k_qkv(const u16* __restrict__ norm,
                                             const u16* __restrict__ Bt,
                                             u16* __restrict__ Qo,
                                             u16* __restrict__ Ko,
                                             u16* __restrict__ Vo)
{
    int m0 = blockIdx.x * 64, j0 = blockIdx.y * 128;
    int t = threadIdx.x, w = t >> 6, lane = t & 63, quad = lane >> 4, l16 = lane & 15;
    const u16* Ap = norm + (long)(m0 + w * 16 + l16) * 256;
    const u16* Bp = Bt + (long)j0 * 256;
    f32x4 z = {0.f, 0.f, 0.f, 0.f};
    f32x4 acc[8];
    #pragma unroll
    for (int j = 0; j < 8; j++) acc[j] = z;
    #pragma unroll
    for (int kc = 0; kc < 8; kc++) {
        bf16x8 a = *(const bf16x8*)&Ap[kc * 32 + quad * 8];
        #pragma unroll
        for (int j = 0; j < 8; j++) {
            bf16x8 b = *(const bf16x8*)&Bp[(long)(j * 16 + l16) * 256 + kc * 32 + quad * 8];
            acc[j] = __builtin_amdgcn_mfma_f32_16x16x32_bf16(a, b, acc[j], 0, 0, 0);
        }
    }
    #pragma unroll
    for (int j = 0; j < 8; j++) {
        int col = j0 + j * 16 + l16;
        int which = col >> 8, h = (col >> 6) & 3, d = col & 63;
        u16* dst = (which == 0) ? Qo : (which == 1) ? Ko : Vo;
        #pragma unroll
        for (int r = 0; r < 4; r++) {
            int m = m0 + w * 16 + quad * 4 + r;
            int n = m >> 12, s = m & 4095;
            dst[((n * 4 + h) * SEQ + s) * 64 + d] = f2bf(acc[j][r]);
        }
    }
}

// ---------------------------------------------------------------------------
// Pass 1 (R2-proven): partial column sums D4[qc][nh][k] = sum_q exp(QK^T/64).
// S^T form: K rows in registers, Q staged in LDS. Grid (32, 8, 4).
// ---------------------------------------------------------------------------
__global__ __launch_bounds__(256) void k_pass1(const u16* __restrict__ Q,
                                               const u16* __restrict__ Km,
                                               float* __restrict__ D4)
{
    __shared__ __align__(16) u16 lQ[128][72];
    int nh = blockIdx.y, k0 = blockIdx.x * 128, qc = blockIdx.z;
    const u16* Qh = Q + (long)nh * SEQ * 64;
    const u16* Kh = Km + (long)nh * SEQ * 64;
    int t = threadIdx.x, w = t >> 6, lane = t & 63, quad = lane >> 4, l16 = lane & 15;
    bf16x8 Kf[2][2];
    #pragma unroll
    for (int i = 0; i < 2; i++)
        #pragma unroll
        for (int ch = 0; ch < 2; ch++)
            Kf[i][ch] = *(const bf16x8*)&Kh[(k0 + w * 32 + i * 16 + l16) * 64 + ch * 32 + quad * 8];
    f32x4 z = {0.f, 0.f, 0.f, 0.f};
    float Dacc[2][4] = {{0.f, 0.f, 0.f, 0.f}, {0.f, 0.f, 0.f, 0.f}};
    const float C = 0.015625f * 1.44269504088896f;   // log2(e)/64
    for (int q0 = qc * 1024; q0 < qc * 1024 + 1024; q0 += 128) {
        #pragma unroll
        for (int p = 0; p < 4; p++) {
            int idx = t + p * 256;
            int row = idx >> 3, cc = (idx & 7) * 8;
            *(uint4*)&lQ[row][cc] = *(const uint4*)&Qh[(q0 + row) * 64 + cc];
        }
        __syncthreads();
        #pragma unroll
        for (int j = 0; j < 8; j++) {
            bf16x8 b0 = *(const bf16x8*)&lQ[j * 16 + l16][quad * 8];
            bf16x8 b1 = *(const bf16x8*)&lQ[j * 16 + l16][32 + quad * 8];
            #pragma unroll
            for (int i = 0; i < 2; i++) {
                f32x4 acc = z;
                acc = __builtin_amdgcn_mfma_f32_16x16x32_bf16(Kf[i][0], b0, acc, 0, 0, 0);
                acc = __builtin_amdgcn_mfma_f32_16x16x32_bf16(Kf[i][1], b1, acc, 0, 0, 0);
                #pragma unroll
                for (int r = 0; r < 4; r++) Dacc[i][r] += exp2f(acc[r] * C);
            }
        }
        __syncthreads();
    }
    #pragma unroll
    for (int i = 0; i < 2; i++)
        #pragma unroll
        for (int r = 0; r < 4; r++) {
            float v = Dacc[i][r];
            v += __shfl_xor(v, 1); v += __shfl_xor(v, 2);
            v += __shfl_xor(v, 4); v += __shfl_xor(v, 8);
            if (l16 == 0)
                D4[((long)(qc * NHT + nh)) * SEQ + k0 + w * 32 + i * 16 + quad * 4 + r] = v;
        }
}

// ---------------------------------------------------------------------------
// Scale+transpose V (R2-proven): Vt[nh][d][k] = V[nh][k][d] / D[nh][k].
// ---------------------------------------------------------------------------
__global__ __launch_bounds__(256) void k_scaleV(const u16* __restrict__ V,
                                                const float* __restrict__ D4,
                                                u16* __restrict__ Vt)
{
    __shared__ float tile[64][65];
    int nh = blockIdx.y, k0 = blockIdx.x * 64;
    int t = threadIdx.x;
    int d = t & 63, kk = t >> 6;
    const u16* Vh = V + (long)nh * SEQ * 64;
    for (int p = 0; p < 16; p++) {
        int k = p * 4 + kk;
        float Dv = D4[((long)(0 * NHT + nh)) * SEQ + k0 + k]
                 + D4[((long)(1 * NHT + nh)) * SEQ + k0 + k]
                 + D4[((long)(2 * NHT + nh)) * SEQ + k0 + k]
                 + D4[((long)(3 * NHT + nh)) * SEQ + k0 + k];
        tile[k][d] = bf2f(Vh[(k0 + k) * 64 + d]) * (1.f / Dv);
    }
    __syncthreads();
    int k2 = t & 63, d4 = t >> 6;
    u16* Vth = Vt + (long)nh * 64 * SEQ;
    for (int p = 0; p < 16; p++) {
        int dd = p * 4 + d4;
        Vth[dd * SEQ + k0 + k2] = f2bf(tile[k2][dd]);
    }
}

// ---------------------------------------------------------------------------
// Pass 2 (R3 structure; ONLY change: plain stores to per-chunk partial
// buffers instead of atomics). Grid (64 q-tiles, 8 nh, 4 k-chunks).
// ---------------------------------------------------------------------------
__global__ __launch_bounds__(256) void k_pass2(const u16* __restrict__ Q,
                                               const u16* __restrict__ Km,
                                               const u16* __restrict__ Vt,
                                               float* __restrict__ acat4)
{
    __shared__ __align__(16) u16 lP[64][136];
    int nh = blockIdx.y, q0 = blockIdx.x * 64, kcid = blockIdx.z;
    int kbase = kcid * 1024;
    int n = nh >> 2, h = nh & 3;
    const u16* Qh = Q + (long)nh * SEQ * 64;
    const u16* Kh = Km + (long)nh * SEQ * 64;
    const u16* Vh = Vt + (long)nh * 64 * SEQ;
    int t = threadIdx.x, w = t >> 6, lane = t & 63, quad = lane >> 4, l16 = lane & 15;
    bf16x8 Qf[4][2];
    #pragma unroll
    for (int j = 0; j < 4; j++)
        #pragma unroll
        for (int ch = 0; ch < 2; ch++)
            Qf[j][ch] = *(const bf16x8*)&Qh[(q0 + j * 16 + l16) * 64 + ch * 32 + quad * 8];
    f32x4 z = {0.f, 0.f, 0.f, 0.f};
    f32x4 accO[4];
    #pragma unroll
    for (int jd = 0; jd < 4; jd++) accO[jd] = z;
    const float C = 0.015625f * 1.44269504088896f;

    for (int k0 = kbase; k0 < kbase + 1024; k0 += 128) {
        // ST: wave w computes k rows [w*32, +32) x 64 q, packed writes to lP
        #pragma unroll
        for (int i = 0; i < 2; i++) {
            bf16x8 a0 = *(const bf16x8*)&Kh[(k0 + w * 32 + i * 16 + l16) * 64 + quad * 8];
            bf16x8 a1 = *(const bf16x8*)&Kh[(k0 + w * 32 + i * 16 + l16) * 64 + 32 + quad * 8];
            #pragma unroll
            for (int j = 0; j < 4; j++) {
                f32x4 acc = z;
                acc = __builtin_amdgcn_mfma_f32_16x16x32_bf16(a0, Qf[j][0], acc, 0, 0, 0);
                acc = __builtin_amdgcn_mfma_f32_16x16x32_bf16(a1, Qf[j][1], acc, 0, 0, 0);
                u16 p0 = f2bf(exp2f(acc[0] * C));
                u16 p1 = f2bf(exp2f(acc[1] * C));
                u16 p2 = f2bf(exp2f(acc[2] * C));
                u16 p3 = f2bf(exp2f(acc[3] * C));
                uint2 pk;
                pk.x = (u32)p0 | ((u32)p1 << 16);
                pk.y = (u32)p2 | ((u32)p3 << 16);
                *(uint2*)&lP[j * 16 + l16][w * 32 + i * 16 + quad * 4] = pk;
            }
        }
        __syncthreads();
        // PV: wave w owns q rows [w*16, +16)
        #pragma unroll
        for (int kc = 0; kc < 4; kc++) {
            bf16x8 pa = *(const bf16x8*)&lP[w * 16 + l16][kc * 32 + quad * 8];
            #pragma unroll
            for (int jd = 0; jd < 4; jd++) {
                bf16x8 vb = *(const bf16x8*)&Vh[(jd * 16 + l16) * SEQ + k0 + kc * 32 + quad * 8];
                accO[jd] = __builtin_amdgcn_mfma_f32_16x16x32_bf16(pa, vb, accO[jd], 0, 0, 0);
            }
        }
        __syncthreads();
    }
    float* dst = acat4 + (long)kcid * 8192 * 256;
    #pragma unroll
    for (int jd = 0; jd < 4; jd++)
        #pragma unroll
        for (int r = 0; r < 4; r++) {
            int s = q0 + w * 16 + quad * 4 + r;
            int c = h * 64 + jd * 16 + l16;
            dst[((long)n * SEQ + s) * 256 + c] = accO[jd][r];
        }
}

// ---------------------------------------------------------------------------
// Sum the 4 pass-2 partials into acat. Fully coalesced float4.
// ---------------------------------------------------------------------------
__global__ __launch_bounds__(256) void k_sum4(const float* __restrict__ acat4,
                                              float* __restrict__ acat)
{
    long i = ((long)blockIdx.x * 256 + threadIdx.x) * 4;
    const long STRIDE = (long)8192 * 256;
    float4 a = *(const float4*)&acat4[i];
    float4 b = *(const float4*)&acat4[i + STRIDE];
    float4 c = *(const float4*)&acat4[i + 2 * STRIDE];
    float4 d = *(const float4*)&acat4[i + 3 * STRIDE];
    float4 o = make_float4(a.x + b.x + c.x + d.x, a.y + b.y + c.y + d.y,
                           a.z + b.z + c.z + d.z, a.w + b.w + c.w + d.w);
    *(float4*)&acat[i] = o;
}

// ---------------------------------------------------------------------------
// LN2 (R2-proven): h2 = LN(attn_cat + x^T) bf16.
// ---------------------------------------------------------------------------
__global__ __launch_bounds__(256) void k_ln2(const float* __restrict__ x,
                                             const float* __restrict__ acat,
                                             const float* __restrict__ w,
                                             const float* __restrict__ b,
                                             u16* __restrict__ h2)
{
    __shared__ float tile[32][257];
    __shared__ float mu[32], rs[32];
    int n = blockIdx.y, s0 = blockIdx.x * 32;
    int t = threadIdx.x;
    int sl = t & 31, cg = t >> 5;
    for (int cc = 0; cc < 256; cc += 8) {
        int c = cc + cg;
        tile[sl][c] = x[(n * 256 + c) * SEQ + s0 + sl];
    }
    __syncthreads();
    for (int s = 0; s < 32; s++)
        tile[s][t] += acat[((long)n * SEQ + s0 + s) * 256 + t];
    __syncthreads();
    int wv = t >> 6, l = t & 63;
    for (int rr = 0; rr < 8; rr++) {
        int s = wv * 8 + rr;
        float a0 = tile[s][l], a1 = tile[s][l + 64], a2 = tile[s][l + 128], a3 = tile[s][l + 192];
        float sm = a0 + a1 + a2 + a3;
        float sq = a0 * a0 + a1 * a1 + a2 * a2 + a3 * a3;
        for (int off = 32; off; off >>= 1) { sm += __shfl_xor(sm, off); sq += __shfl_xor(sq, off); }
        if (l == 0) {
            float m = sm * (1.f / 256.f);
            mu[s] = m;
            rs[s] = rsqrtf(sq * (1.f / 256.f) - m * m + 1e-5f);
        }
    }
    __syncthreads();
    float ww = w[t], bb = b[t];
    for (int s = 0; s < 32; s++) {
        float v = (tile[s][t] - mu[s]) * rs[s] * ww + bb;
        h2[((long)n * SEQ + s0 + s) * 256 + t] = f2bf(v);
    }
}

// ---------------------------------------------------------------------------
// MLP1, BARRIER-FREE: wave computes 16 m x 128 j direct. Grid (128, 2).
// ---------------------------------------------------------------------------
__global__ __launch_bounds__(256) void k_mlp1(const u16* __restrict__ h2,
                                              const u16* __restrict__ W1t,
                                              const float* __restrict__ b1,
                                              u16* __restrict__ tbuf)
{
    int m0 = blockIdx.x * 64, j0 = blockIdx.y * 128;
    int t = threadIdx.x, w = t >> 6, lane = t & 63, quad = lane >> 4, l16 = lane & 15;
    const u16* Ap = h2 + (long)(m0 + w * 16 + l16) * 256;
    const u16* Bp = W1t + (long)j0 * 256;
    f32x4 z = {0.f, 0.f, 0.f, 0.f};
    f32x4 acc[8];
    #pragma unroll
    for (int j = 0; j < 8; j++) acc[j] = z;
    #pragma unroll
    for (int kc = 0; kc < 8; kc++) {
        bf16x8 a = *(const bf16x8*)&Ap[kc * 32 + quad * 8];
        #pragma unroll
        for (int j = 0; j < 8; j++) {
            bf16x8 b = *(const bf16x8*)&Bp[(long)(j * 16 + l16) * 256 + kc * 32 + quad * 8];
            acc[j] = __builtin_amdgcn_mfma_f32_16x16x32_bf16(a, b, acc[j], 0, 0, 0);
        }
    }
    #pragma unroll
    for (int j = 0; j < 8; j++) {
        int col = j0 + j * 16 + l16;
        float bj = b1[col];
        #pragma unroll
        for (int r = 0; r < 4; r++) {
            int m = m0 + w * 16 + quad * 4 + r;
            float v = acc[j][r] + bj;
            float g = 0.5f * v * (1.f + erff(v * 0.70710678118f));
            tbuf[(long)m * 256 + col] = f2bf(g);
        }
    }
}

// ---------------------------------------------------------------------------
// MLP2 + residual + fused output transpose (LDS only in epilogue).
// Grid (128 m-tiles, 2 j-tiles).
// ---------------------------------------------------------------------------
__global__ __launch_bounds__(256) void k_mlp2(const u16* __restrict__ tbuf,
                                              const u16* __restrict__ W2t,
                                              const float* __restrict__ b2,
                                              const float* __restrict__ acat,
                                              float* __restrict__ out)
{
    __shared__ float LT[128][68];
    int m0 = blockIdx.x * 64, j0 = blockIdx.y * 128;
    int t = threadIdx.x, w = t >> 6, lane = t & 63, quad = lane >> 4, l16 = lane & 15;
    const u16* Ap = tbuf + (long)(m0 + w * 16 + l16) * 256;
    const u16* Bp = W2t + (long)j0 * 256;
    f32x4 z = {0.f, 0.f, 0.f, 0.f};
    f32x4 acc[8];
    #pragma unroll
    for (int j = 0; j < 8; j++) acc[j] = z;
    #pragma unroll
    for (int kc = 0; kc < 8; kc++) {
        bf16x8 a = *(const bf16x8*)&Ap[kc * 32 + quad * 8];
        #pragma unroll
        for (int j = 0; j < 8; j++) {
            bf16x8 b = *(const bf16x8*)&Bp[(long)(j * 16 + l16) * 256 + kc * 32 + quad * 8];
            acc[j] = __builtin_amdgcn_mfma_f32_16x16x32_bf16(a, b, acc[j], 0, 0, 0);
        }
    }
    #pragma unroll
    for (int j = 0; j < 8; j++) {
        int col = j0 + j * 16 + l16;
        float bj = b2[col];
        #pragma unroll
        for (int r = 0; r < 4; r++) {
            int m = m0 + w * 16 + quad * 4 + r;
            float v = acc[j][r] + bj + acat[(long)m * 256 + col];
            LT[j * 16 + l16][w * 16 + quad * 4 + r] = v;
        }
    }
    __syncthreads();
    int n = m0 >> 12, sbase = m0 & 4095;
    #pragma unroll
    for (int p = 0; p < 8; p++) {
        int row = p * 16 + (t >> 4);
        int ch = (t & 15) * 4;
        float4 v = *(float4*)&LT[row][ch];
        *(float4*)&out[((long)n * 256 + j0 + row) * SEQ + sbase + ch] = v;
    }
}

// ---------------------------------------------------------------------------
extern "C" void kernel_launch(void* const* d_in, const int* in_sizes, int n_in,
                              void* d_out, int out_size, void* d_ws, size_t ws_size,
                              hipStream_t stream) {
    const float* x    = (const float*)d_in[0];
    const float* ln1w = (const float*)d_in[1];
    const float* ln1b = (const float*)d_in[2];
    const float* WQ   = (const float*)d_in[3];
    const float* WK   = (const float*)d_in[4];
    const float* WV   = (const float*)d_in[5];
    const float* ln2w = (const float*)d_in[6];
    const float* ln2b = (const float*)d_in[7];
    const float* W1   = (const float*)d_in[8];
    const float* b1   = (const float*)d_in[9];
    const float* W2   = (const float*)d_in[10];
    const float* b2   = (const float*)d_in[11];
    float* out = (float*)d_out;

    char* p = (char*)d_ws;
    u16* norm   = (u16*)p;   p += (size_t)8192 * 256 * 2;
    u16* BtQKV  = (u16*)p;   p += (size_t)768 * 256 * 2;
    u16* W1t    = (u16*)p;   p += (size_t)256 * 256 * 2;
    u16* W2t    = (u16*)p;   p += (size_t)256 * 256 * 2;
    u16* Qb     = (u16*)p;   p += (size_t)NHT * SEQ * 64 * 2;
    u16* Kb     = (u16*)p;   p += (size_t)NHT * SEQ * 64 * 2;
    u16* Vb     = (u16*)p;   p += (size_t)NHT * SEQ * 64 * 2;
    float* D4   = (float*)p; p += (size_t)4 * NHT * SEQ * 4;
    u16* Vt     = (u16*)p;   p += (size_t)NHT * SEQ * 64 * 2;
    float* acat4= (float*)p; p += (size_t)4 * 8192 * 256 * 4;
    float* acat = (float*)p; p += (size_t)8192 * 256 * 4;
    u16* h2     = (u16*)p;   p += (size_t)8192 * 256 * 2;
    u16* tbuf   = (u16*)p;   p += (size_t)8192 * 256 * 2;

    k_pack<<<1280, 256, 0, stream>>>(WQ, WK, WV, W1, W2, BtQKV, W1t, W2t);
    k_ln1<<<dim3(128, 2), 256, 0, stream>>>(x, ln1w, ln1b, norm);
    k_qkv<<<dim3(128, 6), 256, 0, stream>>>(norm, BtQKV, Qb, Kb, Vb);
    k_pass1<<<dim3(32, 8, 4), 256, 0, stream>>>(Qb, Kb, D4);
    k_scaleV<<<dim3(64, 8), 256, 0, stream>>>(Vb, D4, Vt);
    k_pass2<<<dim3(64, 8, 4), 256, 0, stream>>>(Qb, Kb, Vt, acat4);
    k_sum4<<<2048, 256, 0, stream>>>(acat4, acat);
    k_ln2<<<dim3(128, 2), 256, 0, stream>>>(x, acat, ln2w, ln2b, h2);
    k_mlp1<<<dim3(128, 2), 256, 0, stream>>>(h2, W1t, b1, tbuf);
    k_mlp2<<<dim3(128, 2), 256, 0, stream>>>(tbuf, W2t, b2, acat, out);
}